// Round 3
// baseline (4898.831 us; speedup 1.0000x reference)
//
#include <hip/hip_runtime.h>
#include <math.h>

#define NH   4096
#define KCAT 8192
#define TPTS 16
#define NB   256    // persistent blocks (1 per CU)
#define TPB  512    // 8 waves per block

typedef unsigned short ushort_t;

// ---------------------------------------------------------------------------
// Wave (64-lane) sum reduction
// ---------------------------------------------------------------------------
__device__ __forceinline__ float wave_reduce64(float s) {
#pragma unroll
    for (int off = 32; off > 0; off >>= 1)
        s += __shfl_down(s, off, 64);
    return s;
}

// ---------------------------------------------------------------------------
// fp32 -> bf16 (RNE) pack, bf16x8 unpack
// ---------------------------------------------------------------------------
__device__ __forceinline__ unsigned f2bf_pack2(float lo, float hi) {
    unsigned ul = __float_as_uint(lo);
    unsigned uh = __float_as_uint(hi);
    ul = (ul + 0x7fffu + ((ul >> 16) & 1u)) >> 16;
    uh = (uh + 0x7fffu + ((uh >> 16) & 1u)) >> 16;
    return ul | (uh << 16);
}

__device__ __forceinline__ void bf16x8_to_f32(uint4 w, float* f) {
    f[0] = __uint_as_float(w.x << 16); f[1] = __uint_as_float(w.x & 0xffff0000u);
    f[2] = __uint_as_float(w.y << 16); f[3] = __uint_as_float(w.y & 0xffff0000u);
    f[4] = __uint_as_float(w.z << 16); f[5] = __uint_as_float(w.z & 0xffff0000u);
    f[6] = __uint_as_float(w.w << 16); f[7] = __uint_as_float(w.w & 0xffff0000u);
}

// Each thread converts 8 floats -> 8 bf16
__global__ __launch_bounds__(256) void cvt_bf16_kernel(const float* __restrict__ src,
                                                       ushort_t* __restrict__ dst, int n8) {
    int i = blockIdx.x * 256 + threadIdx.x;
    if (i < n8) {
        const float4* s4 = (const float4*)src;
        float4 a = s4[2 * i], b = s4[2 * i + 1];
        uint4 o;
        o.x = f2bf_pack2(a.x, a.y);
        o.y = f2bf_pack2(a.z, a.w);
        o.z = f2bf_pack2(b.x, b.y);
        o.w = f2bf_pack2(b.z, b.w);
        ((uint4*)dst)[i] = o;
    }
}

// ---------------------------------------------------------------------------
// Two-level grid barrier: 16 leaf counters (128B apart) + root + generation.
// bar layout (ints): leaf[g] at bar[32*g] (g<16), root at bar[32*16],
// gen at bar[32*17]. Zeroed by hipMemsetAsync before the kernel.
// ---------------------------------------------------------------------------
__device__ __forceinline__ void grid_barrier(int* bar, int target) {
    __syncthreads();   // compiler drains this wave's vmem before s_barrier
    if (threadIdx.x == 0) {
        __threadfence();   // agent-scope release of this block's prior writes
        int* leaf = bar + 32 * (blockIdx.x & 15);
        int* root = bar + 32 * 16;
        int* gen  = bar + 32 * 17;
        int a = __hip_atomic_fetch_add(leaf, 1, __ATOMIC_ACQ_REL, __HIP_MEMORY_SCOPE_AGENT);
        bool done = false;
        if (a == 15) {   // last of this 16-block group
            int r = __hip_atomic_fetch_add(root, 1, __ATOMIC_ACQ_REL, __HIP_MEMORY_SCOPE_AGENT);
            if (r == 15) {   // last block overall: reset and release
#pragma unroll
                for (int i = 0; i < 16; ++i)
                    __hip_atomic_store(bar + 32 * i, 0, __ATOMIC_RELAXED, __HIP_MEMORY_SCOPE_AGENT);
                __hip_atomic_store(root, 0, __ATOMIC_RELAXED, __HIP_MEMORY_SCOPE_AGENT);
                __hip_atomic_store(gen, target, __ATOMIC_RELEASE, __HIP_MEMORY_SCOPE_AGENT);
                done = true;
            }
        }
        if (!done) {
            while (__hip_atomic_load(gen, __ATOMIC_ACQUIRE, __HIP_MEMORY_SCOPE_AGENT) < target)
                __builtin_amdgcn_s_sleep(1);
        }
        __threadfence();   // acquire side: invalidate stale cache
    }
    __syncthreads();
}

// ---------------------------------------------------------------------------
// Stage u[c] = h[c] + a_c * k[c] into LDS as packed bf16 (2 cols x 4096).
// Thread t: col c = t>>8, chunk i = t&255 handles elems [8i,8i+8) and
// [8(i+256), 8(i+256)+8) -> conflict-free ds_write_b128.
// ---------------------------------------------------------------------------
__device__ __forceinline__ void stage_u(const float* __restrict__ hp0,
                                        const float* __restrict__ hp1,
                                        const float* __restrict__ kp0,
                                        const float* __restrict__ kp1,
                                        float a0, float a1, uint4* lds4) {
    const int t = threadIdx.x;
    const int c = t >> 8;
    const int i = t & 255;
    const float* hp = c ? hp1 : hp0;
    const float* kp = c ? kp1 : kp0;
    const float a = c ? a1 : a0;
    const float4* h4 = (const float4*)hp;
    const float4* k4 = (const float4*)kp;
#pragma unroll
    for (int half = 0; half < 2; ++half) {
        int ii = i + half * 256;
        float4 ha = h4[2 * ii], hb = h4[2 * ii + 1];
        float4 ka = k4[2 * ii], kb = k4[2 * ii + 1];
        uint4 o;
        o.x = f2bf_pack2(ha.x + a * ka.x, ha.y + a * ka.y);
        o.y = f2bf_pack2(ha.z + a * ka.z, ha.w + a * ka.w);
        o.z = f2bf_pack2(hb.x + a * kb.x, hb.y + a * kb.y);
        o.w = f2bf_pack2(hb.z + a * kb.z, hb.w + a * kb.w);
        lds4[c * 512 + ii] = o;
    }
}

// ---------------------------------------------------------------------------
// 2-row x 2-col matvec from register-resident packed-bf16 weights.
// Lane l covers elems {8l+512j+k : j<8, k<8}. res[row][col] valid on lane 0.
// ---------------------------------------------------------------------------
__device__ __forceinline__ void mv_rows2(const uint4 (&wr)[2][8], const uint4* lds4,
                                         float (&res)[2][2]) {
    const int l = threadIdx.x & 63;
    float a00 = 0.f, a01 = 0.f, a10 = 0.f, a11 = 0.f;
#pragma unroll
    for (int j = 0; j < 8; ++j) {
        uint4 ua = lds4[l + 64 * j];
        uint4 ub = lds4[512 + l + 64 * j];
        float uf0[8], uf1[8], w0[8], w1[8];
        bf16x8_to_f32(ua, uf0);
        bf16x8_to_f32(ub, uf1);
        bf16x8_to_f32(wr[0][j], w0);
        bf16x8_to_f32(wr[1][j], w1);
#pragma unroll
        for (int k = 0; k < 8; ++k) {
            a00 += w0[k] * uf0[k];
            a01 += w0[k] * uf1[k];
            a10 += w1[k] * uf0[k];
            a11 += w1[k] * uf1[k];
        }
    }
    res[0][0] = wave_reduce64(a00);
    res[0][1] = wave_reduce64(a01);
    res[1][0] = wave_reduce64(a10);
    res[1][1] = wave_reduce64(a11);
}

// ---------------------------------------------------------------------------
// Persistent RK4 kernel: whole 15-step chain, weights in registers.
// Grid MUST be NB=256 blocks x TPB=512 (1 block/CU; launch_bounds caps VGPR
// at 256 so an 8-wave block always fits -> all blocks co-resident).
// ---------------------------------------------------------------------------
__global__ __launch_bounds__(TPB, 2) void rk4_persistent(
    const ushort_t* __restrict__ W1b, const ushort_t* __restrict__ W2b,
    const float* __restrict__ b1, const float* __restrict__ b2,
    const float* __restrict__ h_f, const float* __restrict__ h_b,
    const float* __restrict__ tf, const float* __restrict__ tb,
    float* __restrict__ Hg, float* __restrict__ Ag,
    float* __restrict__ Vg, float* __restrict__ Kg,
    float* __restrict__ Hfin, int* __restrict__ bar)
{
    __shared__ uint4 lds4[1024];   // 2 cols x 4096 bf16 = 16 KB

    const int w = threadIdx.x >> 6;
    const int l = threadIdx.x & 63;
    const int r0 = blockIdx.x * 16 + w * 2;

    // ---- preload weights into registers (packed bf16) ----
    uint4 w1r[2][8], w2r[2][8];
    const uint4* W14 = (const uint4*)W1b;
    const uint4* W24 = (const uint4*)W2b;
#pragma unroll
    for (int q = 0; q < 2; ++q)
#pragma unroll
        for (int j = 0; j < 8; ++j) {
            w1r[q][j] = W14[(size_t)(r0 + q) * 512 + l + 64 * j];
            w2r[q][j] = W24[(size_t)(r0 + q) * 512 + l + 64 * j];
        }
    float bias1[2] = {b1[r0], b1[r0 + 1]};
    float bias2[2] = {b2[r0], b2[r0 + 1]};

    int gen = 0;
    const float* hp0 = h_f;
    const float* hp1 = h_b;
    float* acc_dst = Hg;   // receives this step's h_{s+1}; ping-pongs with Ag

    for (int s = 0; s < TPTS - 1; ++s) {
        float dt0 = tf[s + 1] - tf[s];
        float dt1 = tb[s + 1] - tb[s];
#pragma unroll 1
        for (int st = 0; st < 4; ++st) {
            float coef = (st == 0) ? 0.f : (st == 3 ? 1.f : 0.5f);
            // ---- mv1: V = tanh(W1 (H + coef*dt*K) + b1) ----
            stage_u(hp0, hp1, Kg, Kg + NH, coef * dt0, coef * dt1, lds4);
            __syncthreads();
            float rs[2][2];
            mv_rows2(w1r, lds4, rs);
            if (l == 0) {
                Vg[r0]          = tanhf(rs[0][0] + bias1[0]);
                Vg[NH + r0]     = tanhf(rs[0][1] + bias1[0]);
                Vg[r0 + 1]      = tanhf(rs[1][0] + bias1[1]);
                Vg[NH + r0 + 1] = tanhf(rs[1][1] + bias1[1]);
            }
            ++gen; grid_barrier(bar, gen);
            // ---- mv2: K = W2 V + b2 ; ACC += wgt*(dt/6)*K ----
            stage_u(Vg, Vg + NH, Kg, Kg + NH, 0.f, 0.f, lds4);
            __syncthreads();
            mv_rows2(w2r, lds4, rs);
            if (l == 0) {
                float wgt = (st == 1 || st == 2) ? 2.f : 1.f;
#pragma unroll
                for (int q = 0; q < 2; ++q) {
                    float k0v = rs[q][0] + bias2[q];
                    float k1v = rs[q][1] + bias2[q];
                    Kg[r0 + q]      = k0v;
                    Kg[NH + r0 + q] = k1v;
                    float base0 = (st == 0) ? hp0[r0 + q] : acc_dst[r0 + q];
                    float base1 = (st == 0) ? hp1[r0 + q] : acc_dst[NH + r0 + q];
                    float n0 = base0 + wgt * (dt0 / 6.f) * k0v;
                    float n1 = base1 + wgt * (dt1 / 6.f) * k1v;
                    acc_dst[r0 + q]      = n0;
                    acc_dst[NH + r0 + q] = n1;
                    if (s == TPTS - 2 && st == 3) {
                        Hfin[r0 + q]      = n0;
                        Hfin[NH + r0 + q] = n1;
                    }
                }
            }
            ++gen; grid_barrier(bar, gen);
        }
        hp0 = acc_dst;
        hp1 = acc_dst + NH;
        acc_dst = (acc_dst == Hg) ? Ag : Hg;
    }
}

// ===========================================================================
// FP32 fallback RK4 matvecs (only if ws too small for the fast path)
// ===========================================================================
__global__ __launch_bounds__(256) void init_h_kernel(const float* __restrict__ h_f,
                                                     const float* __restrict__ h_b,
                                                     float* __restrict__ H) {
    int i = blockIdx.x * 256 + threadIdx.x;
    H[i]      = h_f[i];
    H[NH + i] = h_b[i];
}

__global__ __launch_bounds__(256) void rk4_mv1_f32(
    const float* __restrict__ W1, const float* __restrict__ b1,
    const float* __restrict__ H,  const float* __restrict__ Kv,
    const float* __restrict__ tf, const float* __restrict__ tb,
    int tidx, float coef, int useK,
    float* __restrict__ V)
{
    const int row  = blockIdx.x * 4 + (threadIdx.x >> 6);
    const int lane = threadIdx.x & 63;
    const float a0 = coef * (tf[tidx + 1] - tf[tidx]);
    const float a1 = coef * (tb[tidx + 1] - tb[tidx]);

    const float4* __restrict__ W4 = (const float4*)(W1 + (size_t)row * NH);
    const float4* __restrict__ x0 = (const float4*)(H);
    const float4* __restrict__ x1 = (const float4*)(H + NH);
    const float4* __restrict__ k0 = (const float4*)(Kv);
    const float4* __restrict__ k1 = (const float4*)(Kv + NH);

    float s0 = 0.f, s1 = 0.f;
    if (useK) {
#pragma unroll 8
        for (int i = 0; i < NH / 4 / 64; ++i) {
            int idx = lane + i * 64;
            float4 w  = W4[idx];
            float4 h0 = x0[idx], h1 = x1[idx];
            float4 p0 = k0[idx], p1 = k1[idx];
            s0 += w.x * (h0.x + a0 * p0.x) + w.y * (h0.y + a0 * p0.y)
                + w.z * (h0.z + a0 * p0.z) + w.w * (h0.w + a0 * p0.w);
            s1 += w.x * (h1.x + a1 * p1.x) + w.y * (h1.y + a1 * p1.y)
                + w.z * (h1.z + a1 * p1.z) + w.w * (h1.w + a1 * p1.w);
        }
    } else {
#pragma unroll 8
        for (int i = 0; i < NH / 4 / 64; ++i) {
            int idx = lane + i * 64;
            float4 w  = W4[idx];
            float4 h0 = x0[idx], h1 = x1[idx];
            s0 += w.x * h0.x + w.y * h0.y + w.z * h0.z + w.w * h0.w;
            s1 += w.x * h1.x + w.y * h1.y + w.z * h1.z + w.w * h1.w;
        }
    }
    s0 = wave_reduce64(s0);
    s1 = wave_reduce64(s1);
    if (lane == 0) {
        float bb = b1[row];
        V[row]      = tanhf(s0 + bb);
        V[NH + row] = tanhf(s1 + bb);
    }
}

__global__ __launch_bounds__(256) void rk4_mv2_f32(
    const float* __restrict__ W2, const float* __restrict__ b2,
    const float* __restrict__ V,
    const float* __restrict__ tf, const float* __restrict__ tb,
    int tidx, float wgt,
    const float* __restrict__ Hbase,
    float* __restrict__ Kout, float* __restrict__ ACC)
{
    const int row  = blockIdx.x * 4 + (threadIdx.x >> 6);
    const int lane = threadIdx.x & 63;

    const float4* __restrict__ W4 = (const float4*)(W2 + (size_t)row * NH);
    const float4* __restrict__ v0 = (const float4*)(V);
    const float4* __restrict__ v1 = (const float4*)(V + NH);

    float s0 = 0.f, s1 = 0.f;
#pragma unroll 8
    for (int i = 0; i < NH / 4 / 64; ++i) {
        int idx = lane + i * 64;
        float4 w = W4[idx];
        float4 a = v0[idx], b = v1[idx];
        s0 += w.x * a.x + w.y * a.y + w.z * a.z + w.w * a.w;
        s1 += w.x * b.x + w.y * b.y + w.z * b.z + w.w * b.w;
    }
    s0 = wave_reduce64(s0);
    s1 = wave_reduce64(s1);
    if (lane == 0) {
        float bb  = b2[row];
        float k0v = s0 + bb;
        float k1v = s1 + bb;
        Kout[row]      = k0v;
        Kout[NH + row] = k1v;
        const float dt0 = tf[tidx + 1] - tf[tidx];
        const float dt1 = tb[tidx + 1] - tb[tidx];
        ACC[row]      = Hbase[row]      + wgt * (dt0 / 6.f) * k0v;
        ACC[NH + row] = Hbase[NH + row] + wgt * (dt1 / 6.f) * k1v;
    }
}

// ---------------------------------------------------------------------------
// GRU / head kernels (fp32 weights; used 1-2x each)
// ---------------------------------------------------------------------------
__global__ __launch_bounds__(256) void build_xcat_kernel(
    const float* __restrict__ x_f, const float* __restrict__ x_b,
    const float* __restrict__ H,
    float* __restrict__ xcat1, float* __restrict__ xcat2)
{
    int i = blockIdx.x * 256 + threadIdx.x;
    float xf = x_f[i], xb = x_b[i];
    xcat1[i]               = xf;
    xcat2[i]               = xf;
    xcat1[KCAT + i]        = xb;
    xcat2[KCAT + i]        = xb;
    xcat1[NH + i]          = H[i];
    xcat1[KCAT + NH + i]   = H[NH + i];
}

__global__ __launch_bounds__(256) void gru_mv1(
    const float* __restrict__ Wi, const float* __restrict__ bi,
    const float* __restrict__ xcat1, const float* __restrict__ H,
    float* __restrict__ G, float* __restrict__ xcat2)
{
    const int row  = blockIdx.x * 4 + (threadIdx.x >> 6);
    const int lane = threadIdx.x & 63;

    const float4* __restrict__ W4 = (const float4*)(Wi + (size_t)row * KCAT);
    const float4* __restrict__ c0 = (const float4*)(xcat1);
    const float4* __restrict__ c1 = (const float4*)(xcat1 + KCAT);

    float s0 = 0.f, s1 = 0.f;
#pragma unroll 8
    for (int i = 0; i < KCAT / 4 / 64; ++i) {
        int idx = lane + i * 64;
        float4 w = W4[idx];
        float4 a = c0[idx], b = c1[idx];
        s0 += w.x * a.x + w.y * a.y + w.z * a.z + w.w * a.w;
        s1 += w.x * b.x + w.y * b.y + w.z * b.z + w.w * b.w;
    }
    s0 = wave_reduce64(s0);
    s1 = wave_reduce64(s1);
    if (lane == 0) {
        float bb = bi[row];
        float g0 = 1.f / (1.f + expf(-(s0 + bb)));
        float g1 = 1.f / (1.f + expf(-(s1 + bb)));
        G[row]      = g0;
        G[NH + row] = g1;
        xcat2[NH + row]        = g0 * H[row];
        xcat2[KCAT + NH + row] = g1 * H[NH + row];
    }
}

__global__ __launch_bounds__(256) void gru_mv2(
    const float* __restrict__ Wi, const float* __restrict__ bi,
    const float* __restrict__ xcat2, const float* __restrict__ H,
    const float* __restrict__ G,
    float* __restrict__ out, float* __restrict__ hcat)
{
    const int row  = blockIdx.x * 4 + (threadIdx.x >> 6);
    const int lane = threadIdx.x & 63;

    const float4* __restrict__ W4 = (const float4*)(Wi + (size_t)row * KCAT);
    const float4* __restrict__ c0 = (const float4*)(xcat2);
    const float4* __restrict__ c1 = (const float4*)(xcat2 + KCAT);

    float s0 = 0.f, s1 = 0.f;
#pragma unroll 8
    for (int i = 0; i < KCAT / 4 / 64; ++i) {
        int idx = lane + i * 64;
        float4 w = W4[idx];
        float4 a = c0[idx], b = c1[idx];
        s0 += w.x * a.x + w.y * a.y + w.z * a.z + w.w * a.w;
        s1 += w.x * b.x + w.y * b.y + w.z * b.z + w.w * b.w;
    }
    s0 = wave_reduce64(s0);
    s1 = wave_reduce64(s1);
    if (lane == 0) {
        float bb  = bi[row];
        float hh0 = tanhf(s0 + bb);
        float hh1 = tanhf(s1 + bb);
        float g0  = G[row], g1 = G[NH + row];
        float hf  = g0 * H[row]      + (1.f - g0) * hh0;
        float hb  = g1 * H[NH + row] + (1.f - g1) * hh1;
        out[NH + row]     = hf;
        out[2 * NH + row] = hb;
        hcat[row]      = hf;
        hcat[NH + row] = hb;
    }
}

__global__ __launch_bounds__(256) void h2o_mv(
    const float* __restrict__ W, const float* __restrict__ b,
    const float* __restrict__ hcat, float* __restrict__ out)
{
    const int row  = blockIdx.x * 4 + (threadIdx.x >> 6);
    const int lane = threadIdx.x & 63;

    const float4* __restrict__ W4 = (const float4*)(W + (size_t)row * KCAT);
    const float4* __restrict__ x4 = (const float4*)(hcat);

    float s = 0.f;
#pragma unroll 8
    for (int i = 0; i < KCAT / 4 / 64; ++i) {
        int idx = lane + i * 64;
        float4 w = W4[idx];
        float4 a = x4[idx];
        s += w.x * a.x + w.y * a.y + w.z * a.z + w.w * a.w;
    }
    s = wave_reduce64(s);
    if (lane == 0)
        out[row] = s + b[row];
}

// ---------------------------------------------------------------------------
extern "C" void kernel_launch(void* const* d_in, const int* in_sizes, int n_in,
                              void* d_out, int out_size, void* d_ws, size_t ws_size,
                              hipStream_t stream) {
    const float* x_f   = (const float*)d_in[0];
    const float* x_b   = (const float*)d_in[1];
    const float* h_f   = (const float*)d_in[2];
    const float* h_b   = (const float*)d_in[3];
    const float* t_f   = (const float*)d_in[4];
    const float* t_b   = (const float*)d_in[5];
    const float* i2h_W = (const float*)d_in[6];
    const float* i2h_b = (const float*)d_in[7];
    const float* h2o_W = (const float*)d_in[8];
    const float* h2o_b = (const float*)d_in[9];
    const float* f_W1  = (const float*)d_in[10];
    const float* f_b1  = (const float*)d_in[11];
    const float* f_W2  = (const float*)d_in[12];
    const float* f_b2  = (const float*)d_in[13];
    float* out = (float*)d_out;

    // ---- workspace layout ----
    float* ws    = (float*)d_ws;
    float* Hg    = ws;                  // 2*NH
    float* Ag    = Hg    + 2 * NH;      // 2*NH
    float* Vg    = Ag    + 2 * NH;      // 2*NH
    float* Kg    = Vg    + 2 * NH;      // 2*NH
    float* Hfin  = Kg    + 2 * NH;      // 2*NH
    float* xcat1 = Hfin  + 2 * NH;      // 2*KCAT
    float* xcat2 = xcat1 + 2 * KCAT;    // 2*KCAT
    float* G     = xcat2 + 2 * KCAT;    // 2*NH
    float* hcat  = G     + 2 * NH;      // KCAT
    int*   bar   = (int*)(hcat + KCAT); // 32*18 ints
    char*  zend  = (char*)(bar + 32 * 18);
    size_t zbytes = (size_t)(zend - (char*)d_ws);
    size_t zalign = (zbytes + 255) & ~(size_t)255;
    ushort_t* W1bf = (ushort_t*)((char*)d_ws + zalign);
    ushort_t* W2bf = W1bf + (size_t)NH * NH;
    size_t need = zalign + 2 * (size_t)NH * NH * sizeof(ushort_t);
    const bool fast = ws_size >= need;

    dim3 blk(256);
    const float* Hfinal;

    if (fast) {
        // zero internal buffers (Kg must be 0 for the coef=0 first stage) + barrier state
        hipMemsetAsync(d_ws, 0, zalign, stream);
        const int n8 = NH * NH / 8;
        cvt_bf16_kernel<<<n8 / 256, blk, 0, stream>>>(f_W1, W1bf, n8);
        cvt_bf16_kernel<<<n8 / 256, blk, 0, stream>>>(f_W2, W2bf, n8);
        rk4_persistent<<<NB, TPB, 0, stream>>>(W1bf, W2bf, f_b1, f_b2, h_f, h_b,
                                               t_f, t_b, Hg, Ag, Vg, Kg, Hfin, bar);
        Hfinal = Hfin;
    } else {
        // fp32 multi-dispatch fallback
        const int mv_grid = NH / 4;
        init_h_kernel<<<NH / 256, blk, 0, stream>>>(h_f, h_b, Hg);
        float* H   = Hg;
        float* ACC = Ag;
        for (int s = 0; s < TPTS - 1; ++s) {
            rk4_mv1_f32<<<mv_grid, blk, 0, stream>>>(f_W1, f_b1, H, Kg, t_f, t_b, s, 0.0f, 0, Vg);
            rk4_mv2_f32<<<mv_grid, blk, 0, stream>>>(f_W2, f_b2, Vg, t_f, t_b, s, 1.0f, H,   Kg, ACC);
            rk4_mv1_f32<<<mv_grid, blk, 0, stream>>>(f_W1, f_b1, H, Kg, t_f, t_b, s, 0.5f, 1, Vg);
            rk4_mv2_f32<<<mv_grid, blk, 0, stream>>>(f_W2, f_b2, Vg, t_f, t_b, s, 2.0f, ACC, Kg, ACC);
            rk4_mv1_f32<<<mv_grid, blk, 0, stream>>>(f_W1, f_b1, H, Kg, t_f, t_b, s, 0.5f, 1, Vg);
            rk4_mv2_f32<<<mv_grid, blk, 0, stream>>>(f_W2, f_b2, Vg, t_f, t_b, s, 2.0f, ACC, Kg, ACC);
            rk4_mv1_f32<<<mv_grid, blk, 0, stream>>>(f_W1, f_b1, H, Kg, t_f, t_b, s, 1.0f, 1, Vg);
            rk4_mv2_f32<<<mv_grid, blk, 0, stream>>>(f_W2, f_b2, Vg, t_f, t_b, s, 1.0f, ACC, Kg, ACC);
            float* tmp = H; H = ACC; ACC = tmp;
        }
        Hfinal = H;
    }

    const int mv_grid = NH / 4;
    build_xcat_kernel<<<NH / 256, blk, 0, stream>>>(x_f, x_b, Hfinal, xcat1, xcat2);
    gru_mv1<<<mv_grid, blk, 0, stream>>>(i2h_W, i2h_b, xcat1, Hfinal, G, xcat2);
    gru_mv2<<<mv_grid, blk, 0, stream>>>(i2h_W, i2h_b, xcat2, Hfinal, G, out, hcat);
    h2o_mv <<<mv_grid, blk, 0, stream>>>(h2o_W, h2o_b, hcat, out);
}

// Round 4
// 1333.522 us; speedup vs baseline: 3.6736x; 3.6736x over previous
//
#include <hip/hip_runtime.h>
#include <math.h>

#define NH   4096
#define KCAT 8192
#define TPTS 16

typedef unsigned short ushort_t;

// ---------------------------------------------------------------------------
// Wave (64-lane) sum reduction
// ---------------------------------------------------------------------------
__device__ __forceinline__ float wave_reduce64(float s) {
#pragma unroll
    for (int off = 32; off > 0; off >>= 1)
        s += __shfl_down(s, off, 64);
    return s;
}

// ---------------------------------------------------------------------------
// fp32 -> bf16 (RNE) packing, bf16x8 unpack
// ---------------------------------------------------------------------------
__device__ __forceinline__ unsigned f2bf_pack2(float lo, float hi) {
    unsigned ul = __float_as_uint(lo);
    unsigned uh = __float_as_uint(hi);
    ul = (ul + 0x7fffu + ((ul >> 16) & 1u)) >> 16;
    uh = (uh + 0x7fffu + ((uh >> 16) & 1u)) >> 16;
    return ul | (uh << 16);
}

__device__ __forceinline__ ushort_t bf16_1(float x) {
    unsigned u = __float_as_uint(x);
    return (ushort_t)((u + 0x7fffu + ((u >> 16) & 1u)) >> 16);
}

__device__ __forceinline__ void bf16x8_to_f32(uint4 w, float* f) {
    f[0] = __uint_as_float(w.x << 16); f[1] = __uint_as_float(w.x & 0xffff0000u);
    f[2] = __uint_as_float(w.y << 16); f[3] = __uint_as_float(w.y & 0xffff0000u);
    f[4] = __uint_as_float(w.z << 16); f[5] = __uint_as_float(w.z & 0xffff0000u);
    f[6] = __uint_as_float(w.w << 16); f[7] = __uint_as_float(w.w & 0xffff0000u);
}

// Each thread converts 8 floats -> 8 bf16
__global__ __launch_bounds__(256) void cvt_bf16_kernel(const float* __restrict__ src,
                                                       ushort_t* __restrict__ dst, int n8) {
    int i = blockIdx.x * 256 + threadIdx.x;
    if (i < n8) {
        const float4* s4 = (const float4*)src;
        float4 a = s4[2 * i], b = s4[2 * i + 1];
        uint4 o;
        o.x = f2bf_pack2(a.x, a.y);
        o.y = f2bf_pack2(a.z, a.w);
        o.z = f2bf_pack2(b.x, b.y);
        o.w = f2bf_pack2(b.z, b.w);
        ((uint4*)dst)[i] = o;
    }
}

// ---------------------------------------------------------------------------
// Init: H (fp32, 2 cols) and Ubf (bf16) = [h_f, h_b]
// ---------------------------------------------------------------------------
__global__ __launch_bounds__(256) void init_hu(const float* __restrict__ h_f,
                                               const float* __restrict__ h_b,
                                               float* __restrict__ H,
                                               ushort_t* __restrict__ Ubf) {
    int i = blockIdx.x * 256 + threadIdx.x;
    float a = h_f[i], b = h_b[i];
    H[i]       = a;  H[NH + i]   = b;
    Ubf[i]     = bf16_1(a);
    Ubf[NH + i] = bf16_1(b);
}

// ===========================================================================
// ODE phase kernels. 512 blocks x 512 threads; wave w of block b owns row
// b*8+w. The 16 KB bf16 input vector (2 cols x 4096) is staged into LDS once
// per block; weight rows stream from global (bf16, L3-resident on re-reads).
// ===========================================================================

// mv1: V[c][row] = tanh( dot(W1[row,:], U[c]) + b1[row] ), U/V packed bf16.
__global__ __launch_bounds__(512, 4) void ode_mv1(
    const ushort_t* __restrict__ W1b, const float* __restrict__ b1,
    const ushort_t* __restrict__ Ubf, ushort_t* __restrict__ Vbf)
{
    __shared__ uint4 uS[1024];   // 2 cols x 4096 bf16 = 16 KB
    const int t = threadIdx.x;
    {
        const uint4* U4 = (const uint4*)Ubf;
        uS[t]       = U4[t];
        uS[t + 512] = U4[t + 512];
    }
    __syncthreads();

    const int l   = t & 63;
    const int row = blockIdx.x * 8 + (t >> 6);
    const uint4* __restrict__ W4 = (const uint4*)(W1b + (size_t)row * NH);

    float s0 = 0.f, s1 = 0.f;
#pragma unroll
    for (int i = 0; i < 8; ++i) {
        int idx = l + 64 * i;
        uint4 wv = W4[idx];
        uint4 u0 = uS[idx];
        uint4 u1 = uS[512 + idx];
        float wf[8], a0[8], a1[8];
        bf16x8_to_f32(wv, wf);
        bf16x8_to_f32(u0, a0);
        bf16x8_to_f32(u1, a1);
#pragma unroll
        for (int k = 0; k < 8; ++k) {
            s0 += wf[k] * a0[k];
            s1 += wf[k] * a1[k];
        }
    }
    s0 = wave_reduce64(s0);
    s1 = wave_reduce64(s1);
    if (l == 0) {
        float bb = b1[row];
        Vbf[row]      = bf16_1(tanhf(s0 + bb));
        Vbf[NH + row] = bf16_1(tanhf(s1 + bb));
    }
}

// mv2: k[c][row] = dot(W2[row,:], V[c]) + b2[row]
//      ACC = (stage==0 ? H : ACC) + wgt*(dt/6)*k
//      stage<3 : U_next = bf16(H + cnext*dt*k)
//      stage==3: H = ACC (in-place, h_{s+1}); U_next = bf16(H)
__global__ __launch_bounds__(512, 4) void ode_mv2(
    const ushort_t* __restrict__ W2b, const float* __restrict__ b2,
    const ushort_t* __restrict__ Vbf,
    const float* __restrict__ tf, const float* __restrict__ tb, int sidx,
    float wgt, float cnext, int stage,
    float* __restrict__ H, float* __restrict__ ACC,
    ushort_t* __restrict__ Ubf)
{
    __shared__ uint4 vS[1024];
    const int t = threadIdx.x;
    {
        const uint4* V4 = (const uint4*)Vbf;
        vS[t]       = V4[t];
        vS[t + 512] = V4[t + 512];
    }
    __syncthreads();

    const int l   = t & 63;
    const int row = blockIdx.x * 8 + (t >> 6);
    const uint4* __restrict__ W4 = (const uint4*)(W2b + (size_t)row * NH);
    const float dt0 = tf[sidx + 1] - tf[sidx];
    const float dt1 = tb[sidx + 1] - tb[sidx];

    float s0 = 0.f, s1 = 0.f;
#pragma unroll
    for (int i = 0; i < 8; ++i) {
        int idx = l + 64 * i;
        uint4 wv = W4[idx];
        uint4 v0 = vS[idx];
        uint4 v1 = vS[512 + idx];
        float wf[8], a0[8], a1[8];
        bf16x8_to_f32(wv, wf);
        bf16x8_to_f32(v0, a0);
        bf16x8_to_f32(v1, a1);
#pragma unroll
        for (int k = 0; k < 8; ++k) {
            s0 += wf[k] * a0[k];
            s1 += wf[k] * a1[k];
        }
    }
    s0 = wave_reduce64(s0);
    s1 = wave_reduce64(s1);
    if (l == 0) {
        float bb = b2[row];
        float k0 = s0 + bb, k1 = s1 + bb;
        float base0 = (stage == 0) ? H[row]      : ACC[row];
        float base1 = (stage == 0) ? H[NH + row] : ACC[NH + row];
        float a0 = base0 + wgt * (dt0 / 6.f) * k0;
        float a1 = base1 + wgt * (dt1 / 6.f) * k1;
        ACC[row]      = a0;
        ACC[NH + row] = a1;
        if (stage == 3) {
            // a = h_{s+1}; safe in-place: this row is touched only by this block
            H[row]      = a0;
            H[NH + row] = a1;
            Ubf[row]      = bf16_1(a0);
            Ubf[NH + row] = bf16_1(a1);
        } else {
            Ubf[row]      = bf16_1(H[row]      + cnext * dt0 * k0);
            Ubf[NH + row] = bf16_1(H[NH + row] + cnext * dt1 * k1);
        }
    }
}

// ===========================================================================
// FP32 fallback RK4 matvecs (only if ws too small for the bf16 path)
// ===========================================================================
__global__ __launch_bounds__(256) void init_h_kernel(const float* __restrict__ h_f,
                                                     const float* __restrict__ h_b,
                                                     float* __restrict__ H) {
    int i = blockIdx.x * 256 + threadIdx.x;
    H[i]      = h_f[i];
    H[NH + i] = h_b[i];
}

__global__ __launch_bounds__(256) void rk4_mv1_f32(
    const float* __restrict__ W1, const float* __restrict__ b1,
    const float* __restrict__ H,  const float* __restrict__ Kv,
    const float* __restrict__ tf, const float* __restrict__ tb,
    int tidx, float coef, int useK,
    float* __restrict__ V)
{
    const int row  = blockIdx.x * 4 + (threadIdx.x >> 6);
    const int lane = threadIdx.x & 63;
    const float a0 = coef * (tf[tidx + 1] - tf[tidx]);
    const float a1 = coef * (tb[tidx + 1] - tb[tidx]);

    const float4* __restrict__ W4 = (const float4*)(W1 + (size_t)row * NH);
    const float4* __restrict__ x0 = (const float4*)(H);
    const float4* __restrict__ x1 = (const float4*)(H + NH);
    const float4* __restrict__ k0 = (const float4*)(Kv);
    const float4* __restrict__ k1 = (const float4*)(Kv + NH);

    float s0 = 0.f, s1 = 0.f;
    if (useK) {
#pragma unroll 8
        for (int i = 0; i < NH / 4 / 64; ++i) {
            int idx = lane + i * 64;
            float4 w  = W4[idx];
            float4 h0 = x0[idx], h1 = x1[idx];
            float4 p0 = k0[idx], p1 = k1[idx];
            s0 += w.x * (h0.x + a0 * p0.x) + w.y * (h0.y + a0 * p0.y)
                + w.z * (h0.z + a0 * p0.z) + w.w * (h0.w + a0 * p0.w);
            s1 += w.x * (h1.x + a1 * p1.x) + w.y * (h1.y + a1 * p1.y)
                + w.z * (h1.z + a1 * p1.z) + w.w * (h1.w + a1 * p1.w);
        }
    } else {
#pragma unroll 8
        for (int i = 0; i < NH / 4 / 64; ++i) {
            int idx = lane + i * 64;
            float4 w  = W4[idx];
            float4 h0 = x0[idx], h1 = x1[idx];
            s0 += w.x * h0.x + w.y * h0.y + w.z * h0.z + w.w * h0.w;
            s1 += w.x * h1.x + w.y * h1.y + w.z * h1.z + w.w * h1.w;
        }
    }
    s0 = wave_reduce64(s0);
    s1 = wave_reduce64(s1);
    if (lane == 0) {
        float bb = b1[row];
        V[row]      = tanhf(s0 + bb);
        V[NH + row] = tanhf(s1 + bb);
    }
}

__global__ __launch_bounds__(256) void rk4_mv2_f32(
    const float* __restrict__ W2, const float* __restrict__ b2,
    const float* __restrict__ V,
    const float* __restrict__ tf, const float* __restrict__ tb,
    int tidx, float wgt,
    const float* __restrict__ Hbase,
    float* __restrict__ Kout, float* __restrict__ ACC)
{
    const int row  = blockIdx.x * 4 + (threadIdx.x >> 6);
    const int lane = threadIdx.x & 63;

    const float4* __restrict__ W4 = (const float4*)(W2 + (size_t)row * NH);
    const float4* __restrict__ v0 = (const float4*)(V);
    const float4* __restrict__ v1 = (const float4*)(V + NH);

    float s0 = 0.f, s1 = 0.f;
#pragma unroll 8
    for (int i = 0; i < NH / 4 / 64; ++i) {
        int idx = lane + i * 64;
        float4 w = W4[idx];
        float4 a = v0[idx], b = v1[idx];
        s0 += w.x * a.x + w.y * a.y + w.z * a.z + w.w * a.w;
        s1 += w.x * b.x + w.y * b.y + w.z * b.z + w.w * b.w;
    }
    s0 = wave_reduce64(s0);
    s1 = wave_reduce64(s1);
    if (lane == 0) {
        float bb  = b2[row];
        float k0v = s0 + bb;
        float k1v = s1 + bb;
        Kout[row]      = k0v;
        Kout[NH + row] = k1v;
        const float dt0 = tf[tidx + 1] - tf[tidx];
        const float dt1 = tb[tidx + 1] - tb[tidx];
        ACC[row]      = Hbase[row]      + wgt * (dt0 / 6.f) * k0v;
        ACC[NH + row] = Hbase[NH + row] + wgt * (dt1 / 6.f) * k1v;
    }
}

// ---------------------------------------------------------------------------
// GRU / head kernels (fp32 weights; used 1-2x each)
// ---------------------------------------------------------------------------
__global__ __launch_bounds__(256) void build_xcat_kernel(
    const float* __restrict__ x_f, const float* __restrict__ x_b,
    const float* __restrict__ H,
    float* __restrict__ xcat1, float* __restrict__ xcat2)
{
    int i = blockIdx.x * 256 + threadIdx.x;
    float xf = x_f[i], xb = x_b[i];
    xcat1[i]               = xf;
    xcat2[i]               = xf;
    xcat1[KCAT + i]        = xb;
    xcat2[KCAT + i]        = xb;
    xcat1[NH + i]          = H[i];
    xcat1[KCAT + NH + i]   = H[NH + i];
}

__global__ __launch_bounds__(256) void gru_mv1(
    const float* __restrict__ Wi, const float* __restrict__ bi,
    const float* __restrict__ xcat1, const float* __restrict__ H,
    float* __restrict__ G, float* __restrict__ xcat2)
{
    const int row  = blockIdx.x * 4 + (threadIdx.x >> 6);
    const int lane = threadIdx.x & 63;

    const float4* __restrict__ W4 = (const float4*)(Wi + (size_t)row * KCAT);
    const float4* __restrict__ c0 = (const float4*)(xcat1);
    const float4* __restrict__ c1 = (const float4*)(xcat1 + KCAT);

    float s0 = 0.f, s1 = 0.f;
#pragma unroll 8
    for (int i = 0; i < KCAT / 4 / 64; ++i) {
        int idx = lane + i * 64;
        float4 w = W4[idx];
        float4 a = c0[idx], b = c1[idx];
        s0 += w.x * a.x + w.y * a.y + w.z * a.z + w.w * a.w;
        s1 += w.x * b.x + w.y * b.y + w.z * b.z + w.w * b.w;
    }
    s0 = wave_reduce64(s0);
    s1 = wave_reduce64(s1);
    if (lane == 0) {
        float bb = bi[row];
        float g0 = 1.f / (1.f + expf(-(s0 + bb)));
        float g1 = 1.f / (1.f + expf(-(s1 + bb)));
        G[row]      = g0;
        G[NH + row] = g1;
        xcat2[NH + row]        = g0 * H[row];
        xcat2[KCAT + NH + row] = g1 * H[NH + row];
    }
}

__global__ __launch_bounds__(256) void gru_mv2(
    const float* __restrict__ Wi, const float* __restrict__ bi,
    const float* __restrict__ xcat2, const float* __restrict__ H,
    const float* __restrict__ G,
    float* __restrict__ out, float* __restrict__ hcat)
{
    const int row  = blockIdx.x * 4 + (threadIdx.x >> 6);
    const int lane = threadIdx.x & 63;

    const float4* __restrict__ W4 = (const float4*)(Wi + (size_t)row * KCAT);
    const float4* __restrict__ c0 = (const float4*)(xcat2);
    const float4* __restrict__ c1 = (const float4*)(xcat2 + KCAT);

    float s0 = 0.f, s1 = 0.f;
#pragma unroll 8
    for (int i = 0; i < KCAT / 4 / 64; ++i) {
        int idx = lane + i * 64;
        float4 w = W4[idx];
        float4 a = c0[idx], b = c1[idx];
        s0 += w.x * a.x + w.y * a.y + w.z * a.z + w.w * a.w;
        s1 += w.x * b.x + w.y * b.y + w.z * b.z + w.w * b.w;
    }
    s0 = wave_reduce64(s0);
    s1 = wave_reduce64(s1);
    if (lane == 0) {
        float bb  = bi[row];
        float hh0 = tanhf(s0 + bb);
        float hh1 = tanhf(s1 + bb);
        float g0  = G[row], g1 = G[NH + row];
        float hf  = g0 * H[row]      + (1.f - g0) * hh0;
        float hb  = g1 * H[NH + row] + (1.f - g1) * hh1;
        out[NH + row]     = hf;
        out[2 * NH + row] = hb;
        hcat[row]      = hf;
        hcat[NH + row] = hb;
    }
}

__global__ __launch_bounds__(256) void h2o_mv(
    const float* __restrict__ W, const float* __restrict__ b,
    const float* __restrict__ hcat, float* __restrict__ out)
{
    const int row  = blockIdx.x * 4 + (threadIdx.x >> 6);
    const int lane = threadIdx.x & 63;

    const float4* __restrict__ W4 = (const float4*)(W + (size_t)row * KCAT);
    const float4* __restrict__ x4 = (const float4*)(hcat);

    float s = 0.f;
#pragma unroll 8
    for (int i = 0; i < KCAT / 4 / 64; ++i) {
        int idx = lane + i * 64;
        float4 w = W4[idx];
        float4 a = x4[idx];
        s += w.x * a.x + w.y * a.y + w.z * a.z + w.w * a.w;
    }
    s = wave_reduce64(s);
    if (lane == 0)
        out[row] = s + b[row];
}

// ---------------------------------------------------------------------------
extern "C" void kernel_launch(void* const* d_in, const int* in_sizes, int n_in,
                              void* d_out, int out_size, void* d_ws, size_t ws_size,
                              hipStream_t stream) {
    const float* x_f   = (const float*)d_in[0];
    const float* x_b   = (const float*)d_in[1];
    const float* h_f   = (const float*)d_in[2];
    const float* h_b   = (const float*)d_in[3];
    const float* t_f   = (const float*)d_in[4];
    const float* t_b   = (const float*)d_in[5];
    const float* i2h_W = (const float*)d_in[6];
    const float* i2h_b = (const float*)d_in[7];
    const float* h2o_W = (const float*)d_in[8];
    const float* h2o_b = (const float*)d_in[9];
    const float* f_W1  = (const float*)d_in[10];
    const float* f_b1  = (const float*)d_in[11];
    const float* f_W2  = (const float*)d_in[12];
    const float* f_b2  = (const float*)d_in[13];
    float* out = (float*)d_out;

    // ---- workspace layout (all offsets 16B-aligned) ----
    float* ws    = (float*)d_ws;
    float* Hg    = ws;                  // 2*NH fp32
    float* ACCg  = Hg    + 2 * NH;      // 2*NH fp32
    float* Vg32  = ACCg  + 2 * NH;      // 2*NH fp32 (fallback V)
    float* Kg32  = Vg32  + 2 * NH;      // 2*NH fp32 (fallback K)
    float* xcat1 = Kg32  + 2 * NH;      // 2*KCAT
    float* xcat2 = xcat1 + 2 * KCAT;    // 2*KCAT
    float* G     = xcat2 + 2 * KCAT;    // 2*NH
    float* hcat  = G     + 2 * NH;      // KCAT
    float* fend  = hcat  + KCAT;
    ushort_t* Ubf = (ushort_t*)fend;            // 2*NH bf16 (16 KB)
    ushort_t* Vbf = Ubf + 2 * NH;               // 2*NH bf16 (16 KB)
    ushort_t* W1b = Vbf + 2 * NH;               // NH*NH bf16 (32 MB)
    ushort_t* W2b = W1b + (size_t)NH * NH;      // NH*NH bf16 (32 MB)
    size_t need = (size_t)((char*)(W2b + (size_t)NH * NH) - (char*)d_ws);
    const bool fast = ws_size >= need;

    dim3 blk(256);

    if (fast) {
        const int n8 = NH * NH / 8;
        cvt_bf16_kernel<<<n8 / 256, blk, 0, stream>>>(f_W1, W1b, n8);
        cvt_bf16_kernel<<<n8 / 256, blk, 0, stream>>>(f_W2, W2b, n8);
        init_hu<<<NH / 256, blk, 0, stream>>>(h_f, h_b, Hg, Ubf);

        for (int s = 0; s < TPTS - 1; ++s) {
            // stage 1: k1 = f(h);           u2 = h + dt/2 k1
            ode_mv1<<<512, 512, 0, stream>>>(W1b, f_b1, Ubf, Vbf);
            ode_mv2<<<512, 512, 0, stream>>>(W2b, f_b2, Vbf, t_f, t_b, s,
                                             1.f, 0.5f, 0, Hg, ACCg, Ubf);
            // stage 2: k2 = f(h+dt/2 k1);   u3 = h + dt/2 k2
            ode_mv1<<<512, 512, 0, stream>>>(W1b, f_b1, Ubf, Vbf);
            ode_mv2<<<512, 512, 0, stream>>>(W2b, f_b2, Vbf, t_f, t_b, s,
                                             2.f, 0.5f, 1, Hg, ACCg, Ubf);
            // stage 3: k3 = f(h+dt/2 k2);   u4 = h + dt k3
            ode_mv1<<<512, 512, 0, stream>>>(W1b, f_b1, Ubf, Vbf);
            ode_mv2<<<512, 512, 0, stream>>>(W2b, f_b2, Vbf, t_f, t_b, s,
                                             2.f, 1.0f, 2, Hg, ACCg, Ubf);
            // stage 4: k4 = f(h+dt k3);     h' = acc + dt/6 k4; u1' = h'
            ode_mv1<<<512, 512, 0, stream>>>(W1b, f_b1, Ubf, Vbf);
            ode_mv2<<<512, 512, 0, stream>>>(W2b, f_b2, Vbf, t_f, t_b, s,
                                             1.f, 0.0f, 3, Hg, ACCg, Ubf);
        }
    } else {
        // fp32 multi-dispatch fallback (ping-pong via Hg/ACCg)
        const int mv_grid = NH / 4;
        init_h_kernel<<<NH / 256, blk, 0, stream>>>(h_f, h_b, Hg);
        float* H   = Hg;
        float* ACC = ACCg;
        for (int s = 0; s < TPTS - 1; ++s) {
            rk4_mv1_f32<<<mv_grid, blk, 0, stream>>>(f_W1, f_b1, H, Kg32, t_f, t_b, s, 0.0f, 0, Vg32);
            rk4_mv2_f32<<<mv_grid, blk, 0, stream>>>(f_W2, f_b2, Vg32, t_f, t_b, s, 1.0f, H,   Kg32, ACC);
            rk4_mv1_f32<<<mv_grid, blk, 0, stream>>>(f_W1, f_b1, H, Kg32, t_f, t_b, s, 0.5f, 1, Vg32);
            rk4_mv2_f32<<<mv_grid, blk, 0, stream>>>(f_W2, f_b2, Vg32, t_f, t_b, s, 2.0f, ACC, Kg32, ACC);
            rk4_mv1_f32<<<mv_grid, blk, 0, stream>>>(f_W1, f_b1, H, Kg32, t_f, t_b, s, 0.5f, 1, Vg32);
            rk4_mv2_f32<<<mv_grid, blk, 0, stream>>>(f_W2, f_b2, Vg32, t_f, t_b, s, 2.0f, ACC, Kg32, ACC);
            rk4_mv1_f32<<<mv_grid, blk, 0, stream>>>(f_W1, f_b1, H, Kg32, t_f, t_b, s, 1.0f, 1, Vg32);
            rk4_mv2_f32<<<mv_grid, blk, 0, stream>>>(f_W2, f_b2, Vg32, t_f, t_b, s, 1.0f, ACC, Kg32, ACC);
            float* tmp = H; H = ACC; ACC = tmp;
        }
        if (H != Hg) {
            // ensure final h lives in Hg for the tail
            hipMemcpyAsync(Hg, H, 2 * NH * sizeof(float), hipMemcpyDeviceToDevice, stream);
        }
    }

    const int mv_grid = NH / 4;
    build_xcat_kernel<<<NH / 256, blk, 0, stream>>>(x_f, x_b, Hg, xcat1, xcat2);
    gru_mv1<<<mv_grid, blk, 0, stream>>>(i2h_W, i2h_b, xcat1, Hg, G, xcat2);
    gru_mv2<<<mv_grid, blk, 0, stream>>>(i2h_W, i2h_b, xcat2, Hg, G, out, hcat);
    h2o_mv <<<mv_grid, blk, 0, stream>>>(h2o_W, h2o_b, hcat, out);
}